// Round 12
// baseline (239.289 us; speedup 1.0000x reference)
//
#include <hip/hip_runtime.h>

#define NP   8192
#define BB   4
#define DIN  32
#define M0   32
#define M1   32
#define M2   64
#define CAP  80
#define CSTR 81            // candidate row stride (odd -> conflict-free)
#define KWV  16            // waves per knn block
#define SEG  (NP / KWV)    // 512 points per wave

typedef float v2f __attribute__((ext_vector_type(2)));

__device__ __forceinline__ float lrelu(float x) { return fmaxf(x, 0.1f * x); }
__device__ __forceinline__ unsigned umin_(unsigned a, unsigned b) { return a < b ? a : b; }
__device__ __forceinline__ unsigned umax_(unsigned a, unsigned b) { return a > b ? a : b; }

// monotonic float->uint key (total order incl. negatives)
__device__ __forceinline__ unsigned fkey(float f) {
    unsigned b = __float_as_uint(f);
    return (b & 0x80000000u) ? ~b : (b | 0x80000000u);
}
__device__ __forceinline__ float funkey(unsigned k) {
    unsigned b = (k & 0x80000000u) ? (k & 0x7fffffffu) : ~k;
    return __uint_as_float(b);
}

// round-to-nearest-even f32 -> bf16 (as uint16 in low bits)
__device__ __forceinline__ unsigned bf16rn(float f) {
    unsigned u = __float_as_uint(f);
    unsigned r = (u >> 16) & 1u;
    return (u + 0x7fffu + r) >> 16;
}

// ---------------------------------------------------------------------------
// Kernel 1: pack pts (AoS float4) and feat = W0[:,3:] @ points stored as bf16
// pairs. Block = 4 waves over the same 64 points; wave w computes outs [8w,8w+8).
// ---------------------------------------------------------------------------
__global__ __launch_bounds__(256) void prep_kernel(
    const float* __restrict__ xyz, const float* __restrict__ points,
    const float* __restrict__ W0, float4* __restrict__ pts4,
    unsigned* __restrict__ featb)
{
    const int tid  = threadIdx.x;
    const int w    = __builtin_amdgcn_readfirstlane(tid >> 6);  // 0..3
    const int lane = tid & 63;
    const int t    = blockIdx.x * 64 + lane;     // point id, 512 blocks
    const int b    = t >> 13;
    const int n    = t & (NP - 1);

    if (w == 0) {
        const float* xb = xyz + (size_t)b * 3 * NP;
        float x = xb[n], y = xb[NP + n], z = xb[2 * NP + n];
        float s = x * x + y * y + z * z;
        pts4[t] = make_float4(x, y, z, s);
    }

    const float* pb = points + (size_t)b * DIN * NP + n;
    float p[DIN];
#pragma unroll
    for (int c = 0; c < DIN; ++c) p[c] = pb[c * NP];

    uint4 outv;
    unsigned* ov = (unsigned*)&outv;
#pragma unroll
    for (int r = 0; r < 4; ++r) {
        int oe = w * 8 + 2 * r;
        float a0 = 0.f, a1 = 0.f;
#pragma unroll
        for (int c = 0; c < DIN; ++c) {
            a0 = fmaf(W0[oe * 35 + 3 + c], p[c], a0);
            a1 = fmaf(W0[(oe + 1) * 35 + 3 + c], p[c], a1);
        }
        ov[r] = bf16rn(a0) | (bf16rn(a1) << 16);
    }
    *(uint4*)(featb + (size_t)t * 16 + w * 4) = outv;
}

// ---------------------------------------------------------------------------
// Kernel 2: exact 16-NN. lane = point; points packed in v2f pairs ONCE;
// query coefficients pre-duplicated in LDS (qcp[q] = [x2,x2][y2,y2][z2,z2]
// [T,T]). 16 waves/block, 64 queries; each lane owns 8 points (4 pairs).
// SOFTWARE-PIPELINED query loops: load qcp[q+1] before computing q, rotate
// registers at the bottom -> the ds_read latency (~120cy) is hidden behind
// the current iteration's VALU instead of exposing lgkmcnt(0) stalls (r11:
// wall = 2x VALU-busy).
// Pass 1: min over 8 pts -> atomicMin skey[q][lane] (64 classes/query).
// T[q] = 16th smallest of 64 class minima -> written into qcp[q][3].
// Pass 2: bit-identical recompute; per-pair precheck; append cand[q*81+pos];
// exact (t,idx)-lex top-16; overflow -> exact full scan.
// Query loops stay `#pragma unroll 1` (full unroll -> 64-VGPR bust -> r8's
// 0.5 GB scratch spill).
// ---------------------------------------------------------------------------
__global__ __launch_bounds__(1024, 4) void knn_kernel(const float4* __restrict__ pts4,
                                                      int* __restrict__ idxout)
{
    __shared__ v2f      qcp[64][4];                 // pre-duplicated coeffs: 2 KB
    __shared__ unsigned skey[64 * 65];              // 16.6 KB class-min keys
    __shared__ int      scnt[64];
    __shared__ float    cand_t[64 * CSTR];          // 20.7 KB
    __shared__ int      cand_i[64 * CSTR];          // 20.7 KB

    const int tid  = threadIdx.x;
    const int w    = __builtin_amdgcn_readfirstlane(tid >> 6);
    const int lane = tid & 63;
    const int blk  = blockIdx.x;           // 512 blocks
    const int b    = blk >> 7;
    const int n0   = (blk & 127) << 6;
    const int bn0  = b * NP;
    const float4* P = pts4 + bn0;

    for (int i = tid; i < 64 * 65; i += 1024) skey[i] = 0xFFFFFFFFu;
    if (tid < 64) {
        float4 q4 = P[n0 + tid];
        qcp[tid][0] = (v2f){-2.f * q4.x, -2.f * q4.x};
        qcp[tid][1] = (v2f){-2.f * q4.y, -2.f * q4.y};
        qcp[tid][2] = (v2f){-2.f * q4.z, -2.f * q4.z};
        qcp[tid][3] = (v2f){0.f, 0.f};
        scnt[tid] = 0;
    }
    __syncthreads();

    // ---- load + pack my 8 points into pairs (once, register-resident) ----
    const int base = w * SEG;
    v2f ptx[4], pty[4], ptz[4], ptw[4];
#pragma unroll
    for (int j = 0; j < 4; ++j) {
        float4 a  = P[base + (2 * j) * 64 + lane];
        float4 b2 = P[base + (2 * j + 1) * 64 + lane];
        ptx[j] = (v2f){a.x, b2.x};  pty[j] = (v2f){a.y, b2.y};
        ptz[j] = (v2f){a.z, b2.z};  ptw[j] = (v2f){a.w, b2.w};
    }

    // ---- pass 1: pipelined per-query min over my 8 points -> class merge ----
    {
        v2f cx = qcp[0][0], cy = qcp[0][1], cz = qcp[0][2];
#pragma unroll 1
        for (int q = 0; q < 64; ++q) {
            const int qn = (q + 1) & 63;
            v2f nx = qcp[qn][0], ny = qcp[qn][1], nz = qcp[qn][2]; // prefetch
            v2f m2 = {1e30f, 1e30f};
#pragma unroll
            for (int j = 0; j < 4; ++j) {
                v2f t = __builtin_elementwise_fma(cx, ptx[j],
                         __builtin_elementwise_fma(cy, pty[j],
                          __builtin_elementwise_fma(cz, ptz[j], ptw[j])));
                m2 = __builtin_elementwise_min(m2, t);
            }
            float mn = fminf(m2.x, m2.y);
            atomicMin(&skey[q * 65 + lane], fkey(mn));
            cx = nx; cy = ny; cz = nz;                             // rotate
        }
    }
    __syncthreads();

    // ---- threshold: 16th smallest of the 64 class minima -> qcp[q][3] ----
    if (tid < 64) {
        unsigned t16[16];
#pragma unroll
        for (int i = 0; i < 16; ++i) t16[i] = 0xFFFFFFFFu;
        for (int c = 0; c < 64; ++c) {
            unsigned d = skey[tid * 65 + c];
            if (d < t16[15]) {
                t16[15] = d;
#pragma unroll
                for (int i = 15; i > 0; --i) {
                    unsigned a = t16[i - 1], cc = t16[i];
                    t16[i - 1] = umin_(a, cc);
                    t16[i]     = umax_(a, cc);
                }
            }
        }
        float T = funkey(t16[15]);
        qcp[tid][3] = (v2f){T, T};
    }
    __syncthreads();

    // ---- pass 2: pipelined bit-identical recompute, per-pair precheck ----
    {
        v2f cx = qcp[0][0], cy = qcp[0][1], cz = qcp[0][2];
        float T = qcp[0][3].x;
#pragma unroll 1
        for (int q = 0; q < 64; ++q) {
            const int qn = (q + 1) & 63;
            v2f nx = qcp[qn][0], ny = qcp[qn][1], nz = qcp[qn][2];
            float nT = qcp[qn][3].x;                               // prefetch
#pragma unroll
            for (int j = 0; j < 4; ++j) {
                v2f t = __builtin_elementwise_fma(cx, ptx[j],
                         __builtin_elementwise_fma(cy, pty[j],
                          __builtin_elementwise_fma(cz, ptz[j], ptw[j])));
                if (fminf(t.x, t.y) <= T) {          // ~32% wave-prob per pair
                    int jb = base + (2 * j) * 64 + lane;
                    if (t.x <= T) {
                        int pos = atomicAdd(&scnt[q], 1);
                        if (pos < CAP) { cand_t[q * CSTR + pos] = t.x; cand_i[q * CSTR + pos] = jb; }
                    }
                    if (t.y <= T) {
                        int pos = atomicAdd(&scnt[q], 1);
                        if (pos < CAP) { cand_t[q * CSTR + pos] = t.y; cand_i[q * CSTR + pos] = jb + 64; }
                    }
                }
            }
            cx = nx; cy = ny; cz = nz; T = nT;                     // rotate
        }
    }
    __syncthreads();

    // ---- exact selection among candidates (thread = query) ----
    if (tid < 64) {
        int cnt = scnt[tid];
        int* outp = idxout + ((bn0 + n0 + tid) << 4);
        float bd[16]; int bi[16];
#pragma unroll
        for (int i = 0; i < 16; ++i) { bd[i] = 3e38f; bi[i] = 0; }
        if (cnt <= CAP) {
            for (int pos = 0; pos < cnt; ++pos) {
                float d = cand_t[tid * CSTR + pos];
                int   j = cand_i[tid * CSTR + pos];
                if ((d < bd[15]) || (d == bd[15] && j < bi[15])) {
                    bd[15] = d; bi[15] = j;
#pragma unroll
                    for (int i = 15; i > 0; --i) {
                        bool sw = (bd[i] < bd[i - 1]) || (bd[i] == bd[i - 1] && bi[i] < bi[i - 1]);
                        float td = bd[i - 1]; int tj = bi[i - 1];
                        bd[i - 1] = sw ? bd[i] : td;  bi[i - 1] = sw ? bi[i] : tj;
                        bd[i]     = sw ? td : bd[i];  bi[i]     = sw ? tj : bi[i];
                    }
                }
            }
        } else {
            // overflow fallback (exact, never expected): identical association
            float cx = qcp[tid][0].x, cy = qcp[tid][1].x, cz = qcp[tid][2].x;
            for (int j = 0; j < NP; ++j) {
                float4 p = P[j];
                float d = fmaf(cx, p.x, fmaf(cy, p.y, fmaf(cz, p.z, p.w)));
                if ((d < bd[15]) || (d == bd[15] && j < bi[15])) {
                    bd[15] = d; bi[15] = j;
#pragma unroll
                    for (int i = 15; i > 0; --i) {
                        bool sw = (bd[i] < bd[i - 1]) || (bd[i] == bd[i - 1] && bi[i] < bi[i - 1]);
                        float td = bd[i - 1]; int tj = bi[i - 1];
                        bd[i - 1] = sw ? bd[i] : td;  bi[i - 1] = sw ? bi[i] : tj;
                        bd[i]     = sw ? td : bd[i];  bi[i]     = sw ? tj : bi[i];
                    }
                }
            }
        }
#pragma unroll
        for (int i = 0; i < 16; ++i) outp[i] = bi[i];
    }
}

// ---------------------------------------------------------------------------
// Kernel 3: gather + conv0/1/2 + max over K. One thread per (n,k) column,
// 256-thread blocks (16 n x 16 k), 2048 blocks. feat gathered as bf16.
// k-max via shfl_xor width 16. (Unchanged — awaiting first counter capture
// once knn drops below it.)
// ---------------------------------------------------------------------------
__global__ __launch_bounds__(256, 4) void conv_kernel(
    const float4* __restrict__ pts4, const unsigned* __restrict__ featb,
    const int* __restrict__ idx,
    const float* __restrict__ W0, const float* __restrict__ W1, const float* __restrict__ W2,
    float* __restrict__ out)
{
    __shared__ float so[M2][17];
    const int tid = threadIdx.x;
    const int k   = tid & 15;
    const int nl  = tid >> 4;              // 0..15
    const int blk = blockIdx.x;            // 2048 blocks
    const int b   = blk >> 9;              // 512 blocks per batch
    const int n0  = (blk & 511) << 4;
    const int n   = n0 + nl;
    const int bn  = b * NP + n;
    const int j   = idx[(bn << 4) + k];
    const int bj  = b * NP + j;

    const float4 pc = pts4[bn];
    const float4 pj = pts4[bj];
    const float rx = pj.x - pc.x, ry = pj.y - pc.y, rz = pj.z - pc.z;

    const uint4* fj = (const uint4*)(featb + (size_t)bj * 16);

    float x0[M0];
#pragma unroll
    for (int g = 0; g < 4; ++g) {
        uint4 u = fj[g];
        const unsigned* uv = (const unsigned*)&u;
#pragma unroll
        for (int r = 0; r < 4; ++r) {
            int o = g * 8 + 2 * r;
            float fe  = __uint_as_float(uv[r] << 16);
            float fo_ = __uint_as_float(uv[r] & 0xffff0000u);
            x0[o]     = lrelu(fmaf(W0[o * 35], rx, fmaf(W0[o * 35 + 1], ry, fmaf(W0[o * 35 + 2], rz, fe))));
            x0[o + 1] = lrelu(fmaf(W0[(o + 1) * 35], rx, fmaf(W0[(o + 1) * 35 + 1], ry, fmaf(W0[(o + 1) * 35 + 2], rz, fo_))));
        }
    }

    float x1[M1];
#pragma unroll
    for (int o = 0; o < M1; ++o) {
        float acc = 0.f;
#pragma unroll
        for (int c = 0; c < M0; ++c) acc = fmaf(W1[o * 32 + c], x0[c], acc);
        x1[o] = lrelu(acc);
    }

#pragma unroll
    for (int o = 0; o < M2; ++o) {
        float acc = 0.f;
#pragma unroll
        for (int c = 0; c < M1; ++c) acc = fmaf(W2[o * 32 + c], x1[c], acc);
        float v = lrelu(acc);
        v = fmaxf(v, __shfl_xor(v, 1, 16));
        v = fmaxf(v, __shfl_xor(v, 2, 16));
        v = fmaxf(v, __shfl_xor(v, 4, 16));
        v = fmaxf(v, __shfl_xor(v, 8, 16));
        if (k == (o & 15)) so[o][nl] = v;
    }
    __syncthreads();
    {
        int o = tid >> 2;                 // 0..63
        int col = (tid & 3) << 2;         // 0,4,8,12
        float4 v = make_float4(so[o][col], so[o][col + 1], so[o][col + 2], so[o][col + 3]);
        *(float4*)(out + ((size_t)(b * M2 + o)) * NP + n0 + col) = v;
    }
}

// ---------------------------------------------------------------------------
extern "C" void kernel_launch(void* const* d_in, const int* in_sizes, int n_in,
                              void* d_out, int out_size, void* d_ws, size_t ws_size,
                              hipStream_t stream)
{
    const float* xyz    = (const float*)d_in[0];
    const float* points = (const float*)d_in[1];
    const float* W0     = (const float*)d_in[2];
    const float* W1     = (const float*)d_in[3];
    const float* W2     = (const float*)d_in[4];
    float* out = (float*)d_out;

    char* ws = (char*)d_ws;
    float4*   pts4  = (float4*)ws;                       // 512 KB
    unsigned* featb = (unsigned*)(ws + 0x100000);        // 2 MB
    int*      idx   = (int*)(ws + 0x300000);             // 2 MB

    prep_kernel<<<BB * NP / 64, 256,  0, stream>>>(xyz, points, W0, pts4, featb);
    knn_kernel <<<BB * NP / 64, 1024, 0, stream>>>(pts4, idx);
    conv_kernel<<<BB * NP / 16, 256,  0, stream>>>(pts4, featb, idx, W0, W1, W2, out);
}

// Round 13
// 235.557 us; speedup vs baseline: 1.0158x; 1.0158x over previous
//
#include <hip/hip_runtime.h>

#define NP   8192
#define BB   4
#define DIN  32
#define M0   32
#define M1   32
#define M2   64
#define CAP  80
#define CSTR 81            // candidate row stride (odd -> conflict-free)
#define KWV  16            // waves per knn block
#define SEG  (NP / KWV)    // 512 points per wave

__device__ __forceinline__ float lrelu(float x) { return fmaxf(x, 0.1f * x); }
__device__ __forceinline__ unsigned umin_(unsigned a, unsigned b) { return a < b ? a : b; }
__device__ __forceinline__ unsigned umax_(unsigned a, unsigned b) { return a > b ? a : b; }

// monotonic float->uint key (total order incl. negatives)
__device__ __forceinline__ unsigned fkey(float f) {
    unsigned b = __float_as_uint(f);
    return (b & 0x80000000u) ? ~b : (b | 0x80000000u);
}
__device__ __forceinline__ float funkey(unsigned k) {
    unsigned b = (k & 0x80000000u) ? (k & 0x7fffffffu) : ~k;
    return __uint_as_float(b);
}

// round-to-nearest-even f32 -> bf16 (as uint16 in low bits)
__device__ __forceinline__ unsigned bf16rn(float f) {
    unsigned u = __float_as_uint(f);
    unsigned r = (u >> 16) & 1u;
    return (u + 0x7fffu + r) >> 16;
}

// ---------------------------------------------------------------------------
// Kernel 1: pack pts4 = (x,y,z,|p|^2), ptsS = (-2x,-2y,-2z,|p|^2) and
// feat = W0[:,3:] @ points stored as bf16 pairs. Block = 4 waves over the
// same 64 points; wave w computes outputs [8w, 8w+8).
// ---------------------------------------------------------------------------
__global__ __launch_bounds__(256) void prep_kernel(
    const float* __restrict__ xyz, const float* __restrict__ points,
    const float* __restrict__ W0, float4* __restrict__ pts4,
    float4* __restrict__ ptsS, unsigned* __restrict__ featb)
{
    const int tid  = threadIdx.x;
    const int w    = __builtin_amdgcn_readfirstlane(tid >> 6);  // 0..3
    const int lane = tid & 63;
    const int t    = blockIdx.x * 64 + lane;     // point id, 512 blocks
    const int b    = t >> 13;
    const int n    = t & (NP - 1);

    if (w == 0) {
        const float* xb = xyz + (size_t)b * 3 * NP;
        float x = xb[n], y = xb[NP + n], z = xb[2 * NP + n];
        float s = x * x + y * y + z * z;
        pts4[t] = make_float4(x, y, z, s);
        ptsS[t] = make_float4(-2.f * x, -2.f * y, -2.f * z, s);
    }

    const float* pb = points + (size_t)b * DIN * NP + n;
    float p[DIN];
#pragma unroll
    for (int c = 0; c < DIN; ++c) p[c] = pb[c * NP];

    uint4 outv;
    unsigned* ov = (unsigned*)&outv;
#pragma unroll
    for (int r = 0; r < 4; ++r) {
        int oe = w * 8 + 2 * r;
        float a0 = 0.f, a1 = 0.f;
#pragma unroll
        for (int c = 0; c < DIN; ++c) {
            a0 = fmaf(W0[oe * 35 + 3 + c], p[c], a0);
            a1 = fmaf(W0[(oe + 1) * 35 + 3 + c], p[c], a1);
        }
        ov[r] = bf16rn(a0) | (bf16rn(a1) << 16);
    }
    *(uint4*)(featb + (size_t)t * 16 + w * 4) = outv;
}

// ---------------------------------------------------------------------------
// Kernel 2: exact 16-NN via SCALAR-PIPE query broadcast. lane = point; each
// lane owns 8 pre-scaled points sp=(-2x,-2y,-2z,|p|^2) in registers.
// Query coords are wave-uniform -> s_load from global in chunks of 8, fed to
// v_fma as SGPR operands: t = qx*sx + qy*sy + qz*sz + sw. NO per-iteration
// ds_read (r11/r12's stall) and no LDS staging of coefficients at all.
// Pass 1: min over 8 pts -> atomicMin skey[q][lane] (64 classes/query).
// T[q] = 16th smallest of 64 class minima (>=16 distinct points <= T).
// Pass 2: bit-identical recompute (same fma association); per-point t<=T
// append to cand[q*81+pos]; exact (t,idx)-lex top-16; overflow -> full scan.
// Chunk loops are `#pragma unroll 1` (full unroll -> VGPR bust -> r8 spill).
// ---------------------------------------------------------------------------
__global__ __launch_bounds__(1024, 4) void knn_kernel(const float4* __restrict__ pts4,
                                                      const float4* __restrict__ ptsS,
                                                      int* __restrict__ idxout)
{
    __shared__ unsigned skey[64 * 65];              // 16.6 KB class-min keys
    __shared__ float    sT[64];
    __shared__ int      scnt[64];
    __shared__ float    cand_t[64 * CSTR];          // 20.7 KB
    __shared__ int      cand_i[64 * CSTR];          // 20.7 KB

    const int tid  = threadIdx.x;
    const int w    = __builtin_amdgcn_readfirstlane(tid >> 6);
    const int lane = tid & 63;
    const int blk  = blockIdx.x;           // 512 blocks
    const int b    = blk >> 7;
    const int n0   = (blk & 127) << 6;
    const int bn0  = b * NP;
    const float4* P  = pts4 + bn0;         // raw (queries, fallback)
    const float4* S  = ptsS + bn0;         // pre-scaled (scan points)
    const float4* Pq = P + n0;             // this block's 64 queries

    for (int i = tid; i < 64 * 65; i += 1024) skey[i] = 0xFFFFFFFFu;
    if (tid < 64) scnt[tid] = 0;
    __syncthreads();

    // ---- load my 8 pre-scaled points once (coalesced, register-resident) ----
    const int base = w * SEG;
    float4 sp[8];
#pragma unroll
    for (int j = 0; j < 8; ++j) sp[j] = S[base + j * 64 + lane];

    // ---- pass 1: chunks of 8 queries via s_load; min over 8 pts ----
#pragma unroll 1
    for (int qc = 0; qc < 8; ++qc) {
        float4 qv[8];
#pragma unroll
        for (int i = 0; i < 8; ++i) qv[i] = Pq[qc * 8 + i];   // uniform -> s_load
#pragma unroll
        for (int i = 0; i < 8; ++i) {
            const float qx = qv[i].x, qy = qv[i].y, qz = qv[i].z;
            float mn = fmaf(qx, sp[0].x, fmaf(qy, sp[0].y, fmaf(qz, sp[0].z, sp[0].w)));
#pragma unroll
            for (int j = 1; j < 8; ++j) {
                float t = fmaf(qx, sp[j].x, fmaf(qy, sp[j].y, fmaf(qz, sp[j].z, sp[j].w)));
                mn = fminf(mn, t);
            }
            atomicMin(&skey[(qc * 8 + i) * 65 + lane], fkey(mn));
        }
    }
    __syncthreads();

    // ---- threshold: 16th smallest of the 64 class minima (thread = query) ----
    if (tid < 64) {
        unsigned t16[16];
#pragma unroll
        for (int i = 0; i < 16; ++i) t16[i] = 0xFFFFFFFFu;
        for (int c = 0; c < 64; ++c) {
            unsigned d = skey[tid * 65 + c];
            if (d < t16[15]) {
                t16[15] = d;
#pragma unroll
                for (int i = 15; i > 0; --i) {
                    unsigned a = t16[i - 1], cc = t16[i];
                    t16[i - 1] = umin_(a, cc);
                    t16[i]     = umax_(a, cc);
                }
            }
        }
        sT[tid] = funkey(t16[15]);
    }
    __syncthreads();

    // ---- pass 2: bit-identical recompute, per-point t<=T append ----
#pragma unroll 1
    for (int qc = 0; qc < 8; ++qc) {
        float4 qv[8];
#pragma unroll
        for (int i = 0; i < 8; ++i) qv[i] = Pq[qc * 8 + i];   // uniform -> s_load
#pragma unroll
        for (int i = 0; i < 8; ++i) {
            const int q = qc * 8 + i;
            const float qx = qv[i].x, qy = qv[i].y, qz = qv[i].z;
            const float T = sT[q];
#pragma unroll
            for (int j = 0; j < 8; ++j) {
                float t = fmaf(qx, sp[j].x, fmaf(qy, sp[j].y, fmaf(qz, sp[j].z, sp[j].w)));
                if (t <= T) {                        // ~15% wave-prob per point
                    int pos = atomicAdd(&scnt[q], 1);
                    if (pos < CAP) {
                        cand_t[q * CSTR + pos] = t;
                        cand_i[q * CSTR + pos] = base + j * 64 + lane;
                    }
                }
            }
        }
    }
    __syncthreads();

    // ---- exact selection among candidates (thread = query) ----
    if (tid < 64) {
        int cnt = scnt[tid];
        int* outp = idxout + ((bn0 + n0 + tid) << 4);
        float bd[16]; int bi[16];
#pragma unroll
        for (int i = 0; i < 16; ++i) { bd[i] = 3e38f; bi[i] = 0; }
        if (cnt <= CAP) {
            for (int pos = 0; pos < cnt; ++pos) {
                float d = cand_t[tid * CSTR + pos];
                int   j = cand_i[tid * CSTR + pos];
                if ((d < bd[15]) || (d == bd[15] && j < bi[15])) {
                    bd[15] = d; bi[15] = j;
#pragma unroll
                    for (int i = 15; i > 0; --i) {
                        bool sw = (bd[i] < bd[i - 1]) || (bd[i] == bd[i - 1] && bi[i] < bi[i - 1]);
                        float td = bd[i - 1]; int tj = bi[i - 1];
                        bd[i - 1] = sw ? bd[i] : td;  bi[i - 1] = sw ? bi[i] : tj;
                        bd[i]     = sw ? td : bd[i];  bi[i]     = sw ? tj : bi[i];
                    }
                }
            }
        } else {
            // overflow fallback (exact, never expected): identical fma form
            float4 q4 = Pq[tid];
            for (int j = 0; j < NP; ++j) {
                float4 s = S[j];
                float d = fmaf(q4.x, s.x, fmaf(q4.y, s.y, fmaf(q4.z, s.z, s.w)));
                if ((d < bd[15]) || (d == bd[15] && j < bi[15])) {
                    bd[15] = d; bi[15] = j;
#pragma unroll
                    for (int i = 15; i > 0; --i) {
                        bool sw = (bd[i] < bd[i - 1]) || (bd[i] == bd[i - 1] && bi[i] < bi[i - 1]);
                        float td = bd[i - 1]; int tj = bi[i - 1];
                        bd[i - 1] = sw ? bd[i] : td;  bi[i - 1] = sw ? bi[i] : tj;
                        bd[i]     = sw ? td : bd[i];  bi[i]     = sw ? tj : bi[i];
                    }
                }
            }
        }
#pragma unroll
        for (int i = 0; i < 16; ++i) outp[i] = bi[i];
    }
}

// ---------------------------------------------------------------------------
// Kernel 3: gather + conv0/1/2 + max over K. One thread per (n,k) column,
// 256-thread blocks (16 n x 16 k), 2048 blocks. feat gathered as bf16.
// k-max via shfl_xor width 16. (Unchanged, known-good.)
// ---------------------------------------------------------------------------
__global__ __launch_bounds__(256, 4) void conv_kernel(
    const float4* __restrict__ pts4, const unsigned* __restrict__ featb,
    const int* __restrict__ idx,
    const float* __restrict__ W0, const float* __restrict__ W1, const float* __restrict__ W2,
    float* __restrict__ out)
{
    __shared__ float so[M2][17];
    const int tid = threadIdx.x;
    const int k   = tid & 15;
    const int nl  = tid >> 4;              // 0..15
    const int blk = blockIdx.x;            // 2048 blocks
    const int b   = blk >> 9;              // 512 blocks per batch
    const int n0  = (blk & 511) << 4;
    const int n   = n0 + nl;
    const int bn  = b * NP + n;
    const int j   = idx[(bn << 4) + k];
    const int bj  = b * NP + j;

    const float4 pc = pts4[bn];
    const float4 pj = pts4[bj];
    const float rx = pj.x - pc.x, ry = pj.y - pc.y, rz = pj.z - pc.z;

    const uint4* fj = (const uint4*)(featb + (size_t)bj * 16);

    float x0[M0];
#pragma unroll
    for (int g = 0; g < 4; ++g) {
        uint4 u = fj[g];
        const unsigned* uv = (const unsigned*)&u;
#pragma unroll
        for (int r = 0; r < 4; ++r) {
            int o = g * 8 + 2 * r;
            float fe  = __uint_as_float(uv[r] << 16);
            float fo_ = __uint_as_float(uv[r] & 0xffff0000u);
            x0[o]     = lrelu(fmaf(W0[o * 35], rx, fmaf(W0[o * 35 + 1], ry, fmaf(W0[o * 35 + 2], rz, fe))));
            x0[o + 1] = lrelu(fmaf(W0[(o + 1) * 35], rx, fmaf(W0[(o + 1) * 35 + 1], ry, fmaf(W0[(o + 1) * 35 + 2], rz, fo_))));
        }
    }

    float x1[M1];
#pragma unroll
    for (int o = 0; o < M1; ++o) {
        float acc = 0.f;
#pragma unroll
        for (int c = 0; c < M0; ++c) acc = fmaf(W1[o * 32 + c], x0[c], acc);
        x1[o] = lrelu(acc);
    }

#pragma unroll
    for (int o = 0; o < M2; ++o) {
        float acc = 0.f;
#pragma unroll
        for (int c = 0; c < M1; ++c) acc = fmaf(W2[o * 32 + c], x1[c], acc);
        float v = lrelu(acc);
        v = fmaxf(v, __shfl_xor(v, 1, 16));
        v = fmaxf(v, __shfl_xor(v, 2, 16));
        v = fmaxf(v, __shfl_xor(v, 4, 16));
        v = fmaxf(v, __shfl_xor(v, 8, 16));
        if (k == (o & 15)) so[o][nl] = v;
    }
    __syncthreads();
    {
        int o = tid >> 2;                 // 0..63
        int col = (tid & 3) << 2;         // 0,4,8,12
        float4 v = make_float4(so[o][col], so[o][col + 1], so[o][col + 2], so[o][col + 3]);
        *(float4*)(out + ((size_t)(b * M2 + o)) * NP + n0 + col) = v;
    }
}

// ---------------------------------------------------------------------------
extern "C" void kernel_launch(void* const* d_in, const int* in_sizes, int n_in,
                              void* d_out, int out_size, void* d_ws, size_t ws_size,
                              hipStream_t stream)
{
    const float* xyz    = (const float*)d_in[0];
    const float* points = (const float*)d_in[1];
    const float* W0     = (const float*)d_in[2];
    const float* W1     = (const float*)d_in[3];
    const float* W2     = (const float*)d_in[4];
    float* out = (float*)d_out;

    char* ws = (char*)d_ws;
    float4*   pts4  = (float4*)ws;                       // 512 KB
    float4*   ptsS  = (float4*)(ws + 0x080000);          // 512 KB (pre-scaled)
    unsigned* featb = (unsigned*)(ws + 0x100000);        // 2 MB
    int*      idx   = (int*)(ws + 0x300000);             // 2 MB

    prep_kernel<<<BB * NP / 64, 256,  0, stream>>>(xyz, points, W0, pts4, ptsS, featb);
    knn_kernel <<<BB * NP / 64, 1024, 0, stream>>>(pts4, ptsS, idx);
    conv_kernel<<<BB * NP / 16, 256,  0, stream>>>(pts4, featb, idx, W0, W1, W2, out);
}

// Round 14
// 232.103 us; speedup vs baseline: 1.0310x; 1.0149x over previous
//
#include <hip/hip_runtime.h>

#define NP   8192
#define BB   4
#define DIN  32
#define M0   32
#define M1   32
#define M2   64
#define CAP  80
#define CSTR 81            // candidate row stride (odd -> conflict-free)
#define KWV  16            // waves per knn block
#define SEG  (NP / KWV)    // 512 points per wave

__device__ __forceinline__ float lrelu(float x) { return fmaxf(x, 0.1f * x); }
__device__ __forceinline__ unsigned umin_(unsigned a, unsigned b) { return a < b ? a : b; }
__device__ __forceinline__ unsigned umax_(unsigned a, unsigned b) { return a > b ? a : b; }

// monotonic float->uint key (total order incl. negatives)
__device__ __forceinline__ unsigned fkey(float f) {
    unsigned b = __float_as_uint(f);
    return (b & 0x80000000u) ? ~b : (b | 0x80000000u);
}
__device__ __forceinline__ float funkey(unsigned k) {
    unsigned b = (k & 0x80000000u) ? (k & 0x7fffffffu) : ~k;
    return __uint_as_float(b);
}

// round-to-nearest-even f32 -> bf16 (as uint16 in low bits)
__device__ __forceinline__ unsigned bf16rn(float f) {
    unsigned u = __float_as_uint(f);
    unsigned r = (u >> 16) & 1u;
    return (u + 0x7fffu + r) >> 16;
}

// max with a DPP-permuted copy: full VALU rate, no DS pipe (vs ds_bpermute
// that __shfl_xor lowers to). CTRL: 0xB1=quad xor1, 0x4E=quad xor2,
// 0x141=row_half_mirror (merge quad pairs), 0x140=row_mirror (merge halves).
template<int CTRL>
__device__ __forceinline__ float fmax_dpp(float v) {
    int s = __builtin_amdgcn_update_dpp(0, __float_as_int(v), CTRL, 0xf, 0xf, true);
    return fmaxf(v, __int_as_float(s));
}

// ---------------------------------------------------------------------------
// Kernel 1: pack pts4 = (x,y,z,|p|^2), ptsS = (-2x,-2y,-2z,|p|^2) and
// feat = W0[:,3:] @ points stored as bf16 pairs. Block = 4 waves over the
// same 64 points; wave w computes outputs [8w, 8w+8).
// ---------------------------------------------------------------------------
__global__ __launch_bounds__(256) void prep_kernel(
    const float* __restrict__ xyz, const float* __restrict__ points,
    const float* __restrict__ W0, float4* __restrict__ pts4,
    float4* __restrict__ ptsS, unsigned* __restrict__ featb)
{
    const int tid  = threadIdx.x;
    const int w    = __builtin_amdgcn_readfirstlane(tid >> 6);  // 0..3
    const int lane = tid & 63;
    const int t    = blockIdx.x * 64 + lane;     // point id, 512 blocks
    const int b    = t >> 13;
    const int n    = t & (NP - 1);

    if (w == 0) {
        const float* xb = xyz + (size_t)b * 3 * NP;
        float x = xb[n], y = xb[NP + n], z = xb[2 * NP + n];
        float s = x * x + y * y + z * z;
        pts4[t] = make_float4(x, y, z, s);
        ptsS[t] = make_float4(-2.f * x, -2.f * y, -2.f * z, s);
    }

    const float* pb = points + (size_t)b * DIN * NP + n;
    float p[DIN];
#pragma unroll
    for (int c = 0; c < DIN; ++c) p[c] = pb[c * NP];

    uint4 outv;
    unsigned* ov = (unsigned*)&outv;
#pragma unroll
    for (int r = 0; r < 4; ++r) {
        int oe = w * 8 + 2 * r;
        float a0 = 0.f, a1 = 0.f;
#pragma unroll
        for (int c = 0; c < DIN; ++c) {
            a0 = fmaf(W0[oe * 35 + 3 + c], p[c], a0);
            a1 = fmaf(W0[(oe + 1) * 35 + 3 + c], p[c], a1);
        }
        ov[r] = bf16rn(a0) | (bf16rn(a1) << 16);
    }
    *(uint4*)(featb + (size_t)t * 16 + w * 4) = outv;
}

// ---------------------------------------------------------------------------
// Kernel 2: exact 16-NN via scalar-pipe query broadcast (r13 structure).
// lane = point; 8 pre-scaled points/lane in registers; queries s_loaded in
// chunks of 8, fed to v_fma as SGPR operands. Pass-1 min chain reshaped to a
// v_min3-friendly tree (fmin is exactly associative -> identical values).
// Chunk loops `#pragma unroll 1` (full unroll -> VGPR bust -> r8 spill).
// ---------------------------------------------------------------------------
__global__ __launch_bounds__(1024, 4) void knn_kernel(const float4* __restrict__ pts4,
                                                      const float4* __restrict__ ptsS,
                                                      int* __restrict__ idxout)
{
    __shared__ unsigned skey[64 * 65];              // 16.6 KB class-min keys
    __shared__ float    sT[64];
    __shared__ int      scnt[64];
    __shared__ float    cand_t[64 * CSTR];          // 20.7 KB
    __shared__ int      cand_i[64 * CSTR];          // 20.7 KB

    const int tid  = threadIdx.x;
    const int w    = __builtin_amdgcn_readfirstlane(tid >> 6);
    const int lane = tid & 63;
    const int blk  = blockIdx.x;           // 512 blocks
    const int b    = blk >> 7;
    const int n0   = (blk & 127) << 6;
    const int bn0  = b * NP;
    const float4* P  = pts4 + bn0;         // raw (queries, fallback)
    const float4* S  = ptsS + bn0;         // pre-scaled (scan points)
    const float4* Pq = P + n0;             // this block's 64 queries

    for (int i = tid; i < 64 * 65; i += 1024) skey[i] = 0xFFFFFFFFu;
    if (tid < 64) scnt[tid] = 0;
    __syncthreads();

    // ---- load my 8 pre-scaled points once (coalesced, register-resident) ----
    const int base = w * SEG;
    float4 sp[8];
#pragma unroll
    for (int j = 0; j < 8; ++j) sp[j] = S[base + j * 64 + lane];

    // ---- pass 1: chunks of 8 queries via s_load; min3-tree over 8 pts ----
#pragma unroll 1
    for (int qc = 0; qc < 8; ++qc) {
        float4 qv[8];
#pragma unroll
        for (int i = 0; i < 8; ++i) qv[i] = Pq[qc * 8 + i];   // uniform -> s_load
#pragma unroll
        for (int i = 0; i < 8; ++i) {
            const float qx = qv[i].x, qy = qv[i].y, qz = qv[i].z;
            float t[8];
#pragma unroll
            for (int j = 0; j < 8; ++j)
                t[j] = fmaf(qx, sp[j].x, fmaf(qy, sp[j].y, fmaf(qz, sp[j].z, sp[j].w)));
            float a = fminf(fminf(t[0], t[1]), t[2]);   // v_min3
            float b2 = fminf(fminf(t[3], t[4]), t[5]);  // v_min3
            float c2 = fminf(fminf(t[6], t[7]), a);     // v_min3
            float mn = fminf(b2, c2);
            atomicMin(&skey[(qc * 8 + i) * 65 + lane], fkey(mn));
        }
    }
    __syncthreads();

    // ---- threshold: 16th smallest of the 64 class minima (thread = query) ----
    if (tid < 64) {
        unsigned t16[16];
#pragma unroll
        for (int i = 0; i < 16; ++i) t16[i] = 0xFFFFFFFFu;
        for (int c = 0; c < 64; ++c) {
            unsigned d = skey[tid * 65 + c];
            if (d < t16[15]) {
                t16[15] = d;
#pragma unroll
                for (int i = 15; i > 0; --i) {
                    unsigned a = t16[i - 1], cc = t16[i];
                    t16[i - 1] = umin_(a, cc);
                    t16[i]     = umax_(a, cc);
                }
            }
        }
        sT[tid] = funkey(t16[15]);
    }
    __syncthreads();

    // ---- pass 2: bit-identical recompute, per-point t<=T append ----
#pragma unroll 1
    for (int qc = 0; qc < 8; ++qc) {
        float4 qv[8];
#pragma unroll
        for (int i = 0; i < 8; ++i) qv[i] = Pq[qc * 8 + i];   // uniform -> s_load
#pragma unroll
        for (int i = 0; i < 8; ++i) {
            const int q = qc * 8 + i;
            const float qx = qv[i].x, qy = qv[i].y, qz = qv[i].z;
            const float T = sT[q];
#pragma unroll
            for (int j = 0; j < 8; ++j) {
                float t = fmaf(qx, sp[j].x, fmaf(qy, sp[j].y, fmaf(qz, sp[j].z, sp[j].w)));
                if (t <= T) {                        // ~16% wave-prob per point
                    int pos = atomicAdd(&scnt[q], 1);
                    if (pos < CAP) {
                        cand_t[q * CSTR + pos] = t;
                        cand_i[q * CSTR + pos] = base + j * 64 + lane;
                    }
                }
            }
        }
    }
    __syncthreads();

    // ---- exact selection among candidates (thread = query) ----
    if (tid < 64) {
        int cnt = scnt[tid];
        int* outp = idxout + ((bn0 + n0 + tid) << 4);
        float bd[16]; int bi[16];
#pragma unroll
        for (int i = 0; i < 16; ++i) { bd[i] = 3e38f; bi[i] = 0; }
        if (cnt <= CAP) {
            for (int pos = 0; pos < cnt; ++pos) {
                float d = cand_t[tid * CSTR + pos];
                int   j = cand_i[tid * CSTR + pos];
                if ((d < bd[15]) || (d == bd[15] && j < bi[15])) {
                    bd[15] = d; bi[15] = j;
#pragma unroll
                    for (int i = 15; i > 0; --i) {
                        bool sw = (bd[i] < bd[i - 1]) || (bd[i] == bd[i - 1] && bi[i] < bi[i - 1]);
                        float td = bd[i - 1]; int tj = bi[i - 1];
                        bd[i - 1] = sw ? bd[i] : td;  bi[i - 1] = sw ? bi[i] : tj;
                        bd[i]     = sw ? td : bd[i];  bi[i]     = sw ? tj : bi[i];
                    }
                }
            }
        } else {
            // overflow fallback (exact, never expected): identical fma form
            float4 q4 = Pq[tid];
            for (int j = 0; j < NP; ++j) {
                float4 s = S[j];
                float d = fmaf(q4.x, s.x, fmaf(q4.y, s.y, fmaf(q4.z, s.z, s.w)));
                if ((d < bd[15]) || (d == bd[15] && j < bi[15])) {
                    bd[15] = d; bi[15] = j;
#pragma unroll
                    for (int i = 15; i > 0; --i) {
                        bool sw = (bd[i] < bd[i - 1]) || (bd[i] == bd[i - 1] && bi[i] < bi[i - 1]);
                        float td = bd[i - 1]; int tj = bi[i - 1];
                        bd[i - 1] = sw ? bd[i] : td;  bi[i - 1] = sw ? bi[i] : tj;
                        bd[i]     = sw ? td : bd[i];  bi[i]     = sw ? tj : bi[i];
                    }
                }
            }
        }
#pragma unroll
        for (int i = 0; i < 16; ++i) outp[i] = bi[i];
    }
}

// ---------------------------------------------------------------------------
// Kernel 3: gather + conv0/1/2 + max over K. One thread per (n,k) column,
// 256-thread blocks (16 n x 16 k), 2048 blocks. feat gathered as bf16.
// k-max via DPP row ops at full VALU rate (replaces 256 ds_bpermute/thread
// that __shfl_xor lowered to — the suspected conv bottleneck).
// ---------------------------------------------------------------------------
__global__ __launch_bounds__(256, 4) void conv_kernel(
    const float4* __restrict__ pts4, const unsigned* __restrict__ featb,
    const int* __restrict__ idx,
    const float* __restrict__ W0, const float* __restrict__ W1, const float* __restrict__ W2,
    float* __restrict__ out)
{
    __shared__ float so[M2][17];
    const int tid = threadIdx.x;
    const int k   = tid & 15;
    const int nl  = tid >> 4;              // 0..15
    const int blk = blockIdx.x;            // 2048 blocks
    const int b   = blk >> 9;              // 512 blocks per batch
    const int n0  = (blk & 511) << 4;
    const int n   = n0 + nl;
    const int bn  = b * NP + n;
    const int j   = idx[(bn << 4) + k];
    const int bj  = b * NP + j;

    const float4 pc = pts4[bn];
    const float4 pj = pts4[bj];
    const float rx = pj.x - pc.x, ry = pj.y - pc.y, rz = pj.z - pc.z;

    const uint4* fj = (const uint4*)(featb + (size_t)bj * 16);

    float x0[M0];
#pragma unroll
    for (int g = 0; g < 4; ++g) {
        uint4 u = fj[g];
        const unsigned* uv = (const unsigned*)&u;
#pragma unroll
        for (int r = 0; r < 4; ++r) {
            int o = g * 8 + 2 * r;
            float fe  = __uint_as_float(uv[r] << 16);
            float fo_ = __uint_as_float(uv[r] & 0xffff0000u);
            x0[o]     = lrelu(fmaf(W0[o * 35], rx, fmaf(W0[o * 35 + 1], ry, fmaf(W0[o * 35 + 2], rz, fe))));
            x0[o + 1] = lrelu(fmaf(W0[(o + 1) * 35], rx, fmaf(W0[(o + 1) * 35 + 1], ry, fmaf(W0[(o + 1) * 35 + 2], rz, fo_))));
        }
    }

    float x1[M1];
#pragma unroll
    for (int o = 0; o < M1; ++o) {
        float acc = 0.f;
#pragma unroll
        for (int c = 0; c < M0; ++c) acc = fmaf(W1[o * 32 + c], x0[c], acc);
        x1[o] = lrelu(acc);
    }

#pragma unroll
    for (int o = 0; o < M2; ++o) {
        float acc = 0.f;
#pragma unroll
        for (int c = 0; c < M1; ++c) acc = fmaf(W2[o * 32 + c], x1[c], acc);
        float v = lrelu(acc);
        // 16-lane max reduce via DPP (VALU-rate, no DS):
        v = fmax_dpp<0xB1>(v);    // quad_perm xor1
        v = fmax_dpp<0x4E>(v);    // quad_perm xor2
        v = fmax_dpp<0x141>(v);   // row_half_mirror: quad0<->1, quad2<->3
        v = fmax_dpp<0x140>(v);   // row_mirror: halves
        if (k == (o & 15)) so[o][nl] = v;
    }
    __syncthreads();
    {
        int o = tid >> 2;                 // 0..63
        int col = (tid & 3) << 2;         // 0,4,8,12
        float4 v = make_float4(so[o][col], so[o][col + 1], so[o][col + 2], so[o][col + 3]);
        *(float4*)(out + ((size_t)(b * M2 + o)) * NP + n0 + col) = v;
    }
}

// ---------------------------------------------------------------------------
extern "C" void kernel_launch(void* const* d_in, const int* in_sizes, int n_in,
                              void* d_out, int out_size, void* d_ws, size_t ws_size,
                              hipStream_t stream)
{
    const float* xyz    = (const float*)d_in[0];
    const float* points = (const float*)d_in[1];
    const float* W0     = (const float*)d_in[2];
    const float* W1     = (const float*)d_in[3];
    const float* W2     = (const float*)d_in[4];
    float* out = (float*)d_out;

    char* ws = (char*)d_ws;
    float4*   pts4  = (float4*)ws;                       // 512 KB
    float4*   ptsS  = (float4*)(ws + 0x080000);          // 512 KB (pre-scaled)
    unsigned* featb = (unsigned*)(ws + 0x100000);        // 2 MB
    int*      idx   = (int*)(ws + 0x300000);             // 2 MB

    prep_kernel<<<BB * NP / 64, 256,  0, stream>>>(xyz, points, W0, pts4, ptsS, featb);
    knn_kernel <<<BB * NP / 64, 1024, 0, stream>>>(pts4, ptsS, idx);
    conv_kernel<<<BB * NP / 16, 256,  0, stream>>>(pts4, featb, idx, W0, W1, W2, out);
}